// Round 6
// baseline (551.508 us; speedup 1.0000x reference)
//
#include <hip/hip_runtime.h>
#include <math.h>

// MaskedBalancedBCELoss — hard-negative mining via radix select on QUANTIZED
// (top-16-bit) float bit patterns. Losses > 0 => uint bit order == value order.
//
// R6: occupancy + fusion round.
//   Q1 (512 thr, 32 waves/CU, work-stealing chunks): stream pred/gt/mask ->
//      counts, pos_sum, neg16[] (u16, 0 = hole), LDS hist (4096 bins:
//      count u32 + sum f32) -> global; LAST block (ticket) runs the select:
//      k, boundary bin B, k_rem, sum_above.
//   Q2 (512 thr): scan neg16 -> 8-bin boundary hist; LAST block finalizes out.
// Fallback (small ws): proven exact R2 pipeline.

#define NBINS1 4096
#define K1_BLOCKS 1024
#define K3_MAX_LOCAL 7168
#define K3_VEC_PER_BLOCK 1792
#define Q_BLOCKS 1024
#define Q_THREADS 512

struct Ctrl {
  unsigned long long pos_cnt;
  unsigned long long neg_cnt;
  unsigned long long k;
  double pos_sum;
  double sum_above;
  unsigned B;        // 13-bit level-1 bin; 0xFFFFFFFF = none (k==0)
  unsigned k_rem;
  unsigned done1, done2, work1, work2;
  unsigned cand_cnt; // fallback only
};

#define LN2F 0.69314718055994530942f

__device__ __forceinline__ float neg_loss_from(float p) {
  return -fmaxf(__log2f(1.0f - p) * LN2F, -100.0f);
}
__device__ __forceinline__ float pos_loss_from(float p) {
  return -fmaxf(__log2f(p) * LN2F, -100.0f);
}

// ====================== FAST PATH ==========================================

// Q1: stream + fused hist + last-block select.
extern "C" __global__ void __launch_bounds__(Q_THREADS, 8)
q1_stream(const float* __restrict__ pred, const float* __restrict__ gt,
          const float* __restrict__ mask, unsigned* __restrict__ neg16_2,
          unsigned short* __restrict__ neg16s, unsigned* __restrict__ hist1,
          double* __restrict__ binsum, Ctrl* __restrict__ ctrl,
          int n4, int n, unsigned nchunks) {
  __shared__ __align__(16) unsigned hcnt[NBINS1];   // 16 KB (reused as sarr)
  __shared__ __align__(16) float    hsum[NBINS1];   // 16 KB (reused as sws)
  __shared__ unsigned long long spc[8], snc[8];
  __shared__ double sps[8];
  __shared__ unsigned s_chunk;
  __shared__ unsigned s_ticket;
  const int T = Q_THREADS;
  int tid = threadIdx.x;

  for (int i = tid; i < NBINS1; i += T) { hcnt[i] = 0u; hsum[i] = 0.0f; }
  __syncthreads();

  unsigned pc = 0, nc = 0;
  double psum = 0.0;
  const float4* p4 = (const float4*)pred;
  const float4* g4 = (const float4*)gt;
  const float4* m4 = (const float4*)mask;
  uint2* o2 = (uint2*)neg16_2;   // one uint2 (4 x u16) per float4 slot
  const int CHUNK = T * 4;       // float4 slots per chunk

  for (;;) {
    if (tid == 0) s_chunk = atomicAdd(&ctrl->work1, 1u);
    __syncthreads();
    unsigned chunk = s_chunk;
    __syncthreads();             // protect s_chunk before next overwrite
    if (chunk >= nchunks) break;
    int i0 = (int)chunk * CHUNK + tid;

    bool inb[4];
    float4 pv[4], gv[4], mv[4];
#pragma unroll
    for (int j = 0; j < 4; j++) {
      int i = i0 + j * T;
      inb[j] = (i < n4);
      if (inb[j]) { pv[j] = p4[i]; gv[j] = g4[i]; mv[j] = m4[i]; }
      else {
        pv[j] = make_float4(0.5f, 0.5f, 0.5f, 0.5f);
        gv[j] = make_float4(0.f, 0.f, 0.f, 0.f);
        mv[j] = make_float4(0.f, 0.f, 0.f, 0.f);
      }
    }
#pragma unroll
    for (int j = 0; j < 4; j++) {
      float pa[4] = {pv[j].x, pv[j].y, pv[j].z, pv[j].w};
      float ga[4] = {gv[j].x, gv[j].y, gv[j].z, gv[j].w};
      float ma[4] = {mv[j].x, mv[j].y, mv[j].z, mv[j].w};
      unsigned q[4];
#pragma unroll
      for (int e = 0; e < 4; e++) {
        bool valid = (ma[e] != 0.0f);
        bool pos = valid & (ga[e] != 0.0f);
        bool neg = valid & (ga[e] == 0.0f);
        float x = neg ? (1.0f - pa[e]) : pa[e];
        float l = -fmaxf(__log2f(x) * LN2F, -100.0f) + 0.0f;  // -0 -> +0
        pc += pos ? 1u : 0u;
        nc += neg ? 1u : 0u;
        psum += pos ? (double)l : 0.0;
        unsigned bits = __float_as_uint(l);
        if (neg) {
          atomicAdd(&hcnt[bits >> 19], 1u);
          atomicAdd(&hsum[bits >> 19], l);
        }
        q[e] = neg ? (bits >> 16) : 0u;   // u16 quantized; 0 = hole
      }
      if (inb[j]) {
        uint2 w;
        w.x = (q[1] << 16) | q[0];
        w.y = (q[3] << 16) | q[2];
        o2[i0 + j * T] = w;
      }
    }
  }
  // scalar tail (n % 4 != 0)
  int gtid = blockIdx.x * blockDim.x + tid;
  int gstride = gridDim.x * blockDim.x;
  for (int i = n4 * 4 + gtid; i < n; i += gstride) {
    float p = pred[i], g = gt[i], m = mask[i];
    bool valid = (m != 0.0f);
    bool pos = valid & (g != 0.0f);
    bool neg = valid & (g == 0.0f);
    float x = neg ? (1.0f - p) : p;
    float l = -fmaxf(__log2f(x) * LN2F, -100.0f) + 0.0f;
    pc += pos ? 1u : 0u;
    nc += neg ? 1u : 0u;
    psum += pos ? (double)l : 0.0;
    unsigned bits = __float_as_uint(l);
    if (neg) {
      atomicAdd(&hcnt[bits >> 19], 1u);
      atomicAdd(&hsum[bits >> 19], l);
    }
    neg16s[i] = neg ? (unsigned short)(bits >> 16) : (unsigned short)0;
  }

  // block reduce pc/nc/psum
  unsigned long long pcl = pc, ncl = nc;
  for (int off = 32; off > 0; off >>= 1) {
    pcl += __shfl_down(pcl, off);
    ncl += __shfl_down(ncl, off);
    psum += __shfl_down(psum, off);
  }
  int wv = tid >> 6, ln = tid & 63;
  if (ln == 0) { spc[wv] = pcl; snc[wv] = ncl; sps[wv] = psum; }
  __syncthreads();   // also completes all LDS hist atomics
  if (tid == 0) {
    unsigned long long tp = 0, tn = 0; double ts = 0.0;
    for (int w = 0; w < T / 64; w++) { tp += spc[w]; tn += snc[w]; ts += sps[w]; }
    atomicAdd(&ctrl->pos_cnt, tp);
    atomicAdd(&ctrl->neg_cnt, tn);
    unsafeAtomicAdd(&ctrl->pos_sum, ts);
  }
  // flush non-empty bins to global
  for (int i = tid; i < NBINS1; i += T) {
    unsigned c = hcnt[i];
    if (c) {
      atomicAdd(&hist1[i], c);
      unsafeAtomicAdd(&binsum[i], (double)hsum[i]);
    }
  }
  __syncthreads();       // all global atomics of this block issued+drained
  __threadfence();
  if (tid == 0) s_ticket = atomicAdd(&ctrl->done1, 1u);
  __syncthreads();
  if (s_ticket != (unsigned)(gridDim.x - 1)) return;
  __threadfence();       // acquire: other blocks' atomics now visible

  // ---------- last block: select (old P2) ----------
  const int CH = NBINS1 / T;                       // 8 bins per thread
  unsigned long long* sarr = (unsigned long long*)hcnt;  // reuse LDS
  double* swsd = (double*)hsum;                          // reuse LDS
  __shared__ unsigned long long sk;
  __shared__ unsigned sB, skrem;
  int t = tid;

  unsigned cnt[CH];
  unsigned long long tot = 0;
  for (int j = 0; j < CH; j++) { cnt[j] = hist1[t * CH + j]; tot += cnt[j]; }
  __syncthreads();   // hcnt reads done long ago; safe to overwrite
  sarr[t] = tot;
  if (t == 0) {
    sB = 0xFFFFFFFFu; skrem = 0u;
    unsigned long long pos = ctrl->pos_cnt, negtot = ctrl->neg_cnt;
    unsigned long long k = 0;
    if (pos > 0) {
      k = pos * 3ull;            // floor(pos*3.0), exact in integer
      if (k > negtot) k = negtot;
    }
    ctrl->k = k;
    sk = k;
  }
  __syncthreads();
  // inclusive suffix scan
  for (int off = 1; off < T; off <<= 1) {
    unsigned long long v = (t + off < T) ? sarr[t + off] : 0ull;
    __syncthreads();
    sarr[t] += v;
    __syncthreads();
  }
  unsigned long long k = sk;
  if (k > 0) {
    unsigned long long above = sarr[t] - tot;
    if (above < k && sarr[t] >= k) {
      unsigned long long cum = above;
      for (int j = CH - 1; j >= 0; j--) {
        if (cum + (unsigned long long)cnt[j] >= k) {
          sB = (unsigned)(t * CH + j);
          skrem = (unsigned)(k - cum);
          break;
        }
        cum += cnt[j];
      }
    }
  }
  __syncthreads();
  unsigned B = sB;
  if (t == 0) { ctrl->B = B; ctrl->k_rem = skrem; }

  // sum_above = sum of binsum[b] for b > B
  double s = 0.0;
  if (B != 0xFFFFFFFFu) {
    for (unsigned i = t; i < NBINS1; i += T)
      if (i > B) s += binsum[i];
  }
  for (int off = 32; off > 0; off >>= 1) s += __shfl_down(s, off);
  if (ln == 0) swsd[wv] = s;
  __syncthreads();
  if (t == 0) {
    double ss = 0.0;
    for (int w = 0; w < T / 64; w++) ss += swsd[w];
    ctrl->sum_above = ss;
  }
}

// Q2: scan neg16 -> 8-bin boundary hist; last block finalizes output.
extern "C" __global__ void __launch_bounds__(Q_THREADS, 8)
q2_scan(const uint4* __restrict__ neg16_4,
        const unsigned short* __restrict__ neg16s,
        Ctrl* __restrict__ ctrl, unsigned* __restrict__ h3,
        float* __restrict__ out, int n16, int n, unsigned nchunks) {
  __shared__ unsigned lh[8];
  __shared__ unsigned s_chunk;
  __shared__ unsigned s_ticket;
  const int T = Q_THREADS;
  int tid = threadIdx.x;
  if (tid < 8) lh[tid] = 0u;
  __syncthreads();

  const unsigned B = ctrl->B;   // 0xFFFFFFFF => never matches
  const int CHUNK = T * 4;      // uint4 slots per chunk

  for (;;) {
    if (tid == 0) s_chunk = atomicAdd(&ctrl->work2, 1u);
    __syncthreads();
    unsigned chunk = s_chunk;
    __syncthreads();
    if (chunk >= nchunks) break;
    int i0 = (int)chunk * CHUNK + tid;
    uint4 vv[4];
#pragma unroll
    for (int j = 0; j < 4; j++) {
      int i = i0 + j * T;
      vv[j] = (i < n16) ? neg16_4[i] : make_uint4(0u, 0u, 0u, 0u);
    }
#pragma unroll
    for (int j = 0; j < 4; j++) {
      unsigned wa[4] = {vv[j].x, vv[j].y, vv[j].z, vv[j].w};
#pragma unroll
      for (int e = 0; e < 4; e++) {
        unsigned lo = wa[e] & 0xFFFFu;
        unsigned hi = wa[e] >> 16;
        if ((lo >> 3) == B) atomicAdd(&lh[lo & 7u], 1u);
        if ((hi >> 3) == B) atomicAdd(&lh[hi & 7u], 1u);
      }
    }
  }
  int gtid = blockIdx.x * blockDim.x + tid;
  int gstride = gridDim.x * blockDim.x;
  for (int i = n16 * 8 + gtid; i < n; i += gstride) {
    unsigned v = (unsigned)neg16s[i];
    if ((v >> 3) == B) atomicAdd(&lh[v & 7u], 1u);
  }
  __syncthreads();
  if (tid < 8) {
    unsigned c = lh[tid];
    if (c) atomicAdd(&h3[tid], c);
  }
  __syncthreads();
  __threadfence();
  if (tid == 0) s_ticket = atomicAdd(&ctrl->done2, 1u);
  __syncthreads();
  if (s_ticket != (unsigned)(gridDim.x - 1)) return;
  __threadfence();

  if (tid == 0) {
    double partial = 0.0;
    unsigned rem = ctrl->k_rem;
    unsigned Bb = ctrl->B;
    if (rem > 0 && Bb != 0xFFFFFFFFu) {
      for (int b = 7; b >= 0 && rem > 0; b--) {
        unsigned c = h3[b];
        if (!c) continue;
        unsigned take = (c < rem) ? c : rem;
        float val = __uint_as_float(((Bb << 3) | (unsigned)b) << 16);
        partial += (double)take * (double)val;
        rem -= take;
      }
    }
    double neg_sum = ctrl->sum_above + partial;
    double denom = (double)ctrl->pos_cnt + (double)ctrl->k + 1e-6;
    out[0] = (float)((ctrl->pos_sum + neg_sum) / denom);
  }
}

// ====================== FALLBACK (proven R2 exact pipeline) ================

extern "C" __global__ void __launch_bounds__(256)
k1_hist(const float* __restrict__ pred, const float* __restrict__ gt,
        const float* __restrict__ mask, unsigned* __restrict__ hist1,
        Ctrl* __restrict__ ctrl, int n4, int n) {
  __shared__ unsigned h[NBINS1];
  for (int i = threadIdx.x; i < NBINS1; i += blockDim.x) h[i] = 0u;
  __syncthreads();
  unsigned pc = 0, nc = 0;
  double psum = 0.0;
  const float4* p4 = (const float4*)pred;
  const float4* g4 = (const float4*)gt;
  const float4* m4 = (const float4*)mask;
  int gtid = blockIdx.x * blockDim.x + threadIdx.x;
  int stride = gridDim.x * blockDim.x;
  for (int i = gtid; i < n4; i += stride) {
    float4 pv = p4[i], gv = g4[i], mv = m4[i];
    float pa[4] = {pv.x, pv.y, pv.z, pv.w};
    float ga[4] = {gv.x, gv.y, gv.z, gv.w};
    float ma[4] = {mv.x, mv.y, mv.z, mv.w};
#pragma unroll
    for (int j = 0; j < 4; j++) {
      if (ma[j] != 0.0f) {
        if (ga[j] != 0.0f) { pc++; psum += (double)pos_loss_from(pa[j]); }
        else {
          nc++;
          atomicAdd(&h[__float_as_uint(neg_loss_from(pa[j])) >> 19], 1u);
        }
      }
    }
  }
  for (int i = n4 * 4 + gtid; i < n; i += stride) {
    float p = pred[i], g = gt[i], m = mask[i];
    if (m != 0.0f) {
      if (g != 0.0f) { pc++; psum += (double)pos_loss_from(p); }
      else { nc++; atomicAdd(&h[__float_as_uint(neg_loss_from(p)) >> 19], 1u); }
    }
  }
  unsigned long long pcl = pc, ncl = nc;
  for (int off = 32; off > 0; off >>= 1) {
    pcl += __shfl_down(pcl, off);
    ncl += __shfl_down(ncl, off);
    psum += __shfl_down(psum, off);
  }
  __shared__ unsigned long long spc[4], snc[4];
  __shared__ double sps[4];
  int wv = threadIdx.x >> 6, ln = threadIdx.x & 63;
  if (ln == 0) { spc[wv] = pcl; snc[wv] = ncl; sps[wv] = psum; }
  __syncthreads();
  if (threadIdx.x == 0) {
    unsigned long long tp = 0, tn = 0; double ts = 0.0;
    for (int w = 0; w < 4; w++) { tp += spc[w]; tn += snc[w]; ts += sps[w]; }
    atomicAdd(&ctrl->pos_cnt, tp);
    atomicAdd(&ctrl->neg_cnt, tn);
    unsafeAtomicAdd(&ctrl->pos_sum, ts);
  }
  for (int i = threadIdx.x; i < NBINS1; i += blockDim.x) {
    unsigned c = h[i];
    if (c) atomicAdd(&hist1[i], c);
  }
}

extern "C" __global__ void __launch_bounds__(256)
k2_select_fb(const unsigned* __restrict__ hist1, Ctrl* __restrict__ ctrl) {
  const int T = 256, CH = NBINS1 / T;
  __shared__ unsigned long long sarr[T];
  __shared__ unsigned long long sk;
  int t = threadIdx.x;
  unsigned cnt[CH];
  unsigned long long tot = 0;
  for (int j = 0; j < CH; j++) { cnt[j] = hist1[t * CH + j]; tot += cnt[j]; }
  sarr[t] = tot;
  __syncthreads();
  for (int off = 1; off < T; off <<= 1) {
    unsigned long long v = (t + off < T) ? sarr[t + off] : 0ull;
    __syncthreads();
    sarr[t] += v;
    __syncthreads();
  }
  if (t == 0) {
    unsigned long long pos = ctrl->pos_cnt, negtot = ctrl->neg_cnt;
    unsigned long long k = 0;
    if (pos > 0) {
      k = pos * 3ull;
      if (k > negtot) k = negtot;
    }
    ctrl->k = k;
    sk = k;
    if (k == 0) { ctrl->B = 0xFFFFFFFFu; ctrl->k_rem = 0u; }
  }
  __syncthreads();
  unsigned long long k = sk;
  if (k > 0) {
    unsigned long long above = sarr[t] - tot;
    if (above < k && sarr[t] >= k) {
      unsigned long long cum = above;
      for (int j = CH - 1; j >= 0; j--) {
        if (cum + (unsigned long long)cnt[j] >= k) {
          ctrl->B = (unsigned)(t * CH + j);
          ctrl->k_rem = (unsigned)(k - cum);
          break;
        }
        cum += cnt[j];
      }
    }
  }
}

extern "C" __global__ void __launch_bounds__(256)
k3_compact(const float* __restrict__ pred, const float* __restrict__ gt,
           const float* __restrict__ mask, Ctrl* __restrict__ ctrl,
           unsigned* __restrict__ cand, unsigned cap, int n4, int n) {
  __shared__ unsigned lbuf[K3_MAX_LOCAL];
  __shared__ unsigned lcnt;
  __shared__ unsigned gbase;
  __shared__ double sws[4];
  if (threadIdx.x == 0) { lcnt = 0u; gbase = 0u; }
  __syncthreads();
  const unsigned B = ctrl->B;
  double ssum = 0.0;
  const float4* p4 = (const float4*)pred;
  const float4* g4 = (const float4*)gt;
  const float4* m4 = (const float4*)mask;
  int gtid = blockIdx.x * blockDim.x + threadIdx.x;
  int stride = gridDim.x * blockDim.x;
  for (int i = gtid; i < n4; i += stride) {
    float4 pv = p4[i], gv = g4[i], mv = m4[i];
    float pa[4] = {pv.x, pv.y, pv.z, pv.w};
    float ga[4] = {gv.x, gv.y, gv.z, gv.w};
    float ma[4] = {mv.x, mv.y, mv.z, mv.w};
#pragma unroll
    for (int j = 0; j < 4; j++) {
      if (ma[j] != 0.0f && ga[j] == 0.0f) {
        float loss = neg_loss_from(pa[j]);
        unsigned bits = __float_as_uint(loss);
        unsigned b = bits >> 19;
        if (B != 0xFFFFFFFFu && b > B) ssum += (double)loss;
        else if (b == B) {
          unsigned idx = atomicAdd(&lcnt, 1u);
          if (idx < K3_MAX_LOCAL) lbuf[idx] = bits;
        }
      }
    }
  }
  for (int i = n4 * 4 + gtid; i < n; i += stride) {
    float p = pred[i], g = gt[i], m = mask[i];
    if (m != 0.0f && g == 0.0f) {
      float loss = neg_loss_from(p);
      unsigned bits = __float_as_uint(loss);
      unsigned b = bits >> 19;
      if (B != 0xFFFFFFFFu && b > B) ssum += (double)loss;
      else if (b == B) {
        unsigned idx = atomicAdd(&lcnt, 1u);
        if (idx < K3_MAX_LOCAL) lbuf[idx] = bits;
      }
    }
  }
  for (int off = 32; off > 0; off >>= 1) ssum += __shfl_down(ssum, off);
  int wv = threadIdx.x >> 6, ln = threadIdx.x & 63;
  if (ln == 0) sws[wv] = ssum;
  __syncthreads();
  if (threadIdx.x == 0) {
    unsafeAtomicAdd(&ctrl->sum_above, sws[0] + sws[1] + sws[2] + sws[3]);
    unsigned c = lcnt;
    if (c > K3_MAX_LOCAL) c = K3_MAX_LOCAL;
    lcnt = c;
    gbase = c ? atomicAdd(&ctrl->cand_cnt, c) : 0u;
  }
  __syncthreads();
  unsigned c = lcnt, base = gbase;
  for (unsigned i = threadIdx.x; i < c; i += blockDim.x) {
    unsigned dst = base + i;
    if (dst < cap) cand[dst] = lbuf[i];
  }
}

extern "C" __global__ void __launch_bounds__(1024)
k4_final(const unsigned* __restrict__ cand, Ctrl* __restrict__ ctrl,
         float* __restrict__ out, unsigned cap) {
  const int T = 1024, CH2 = 4096 / T;
  __shared__ unsigned h2[4096];
  __shared__ unsigned h3[128];
  __shared__ unsigned long long sarr[T];
  __shared__ int sB2;
  __shared__ unsigned sk2;
  __shared__ double sws[16];
  int t = threadIdx.x;
  unsigned M = ctrl->cand_cnt; if (M > cap) M = cap;
  unsigned k_rem = ctrl->k_rem;
  for (int i = t; i < 4096; i += T) h2[i] = 0u;
  for (int i = t; i < 128; i += T) h3[i] = 0u;
  if (t == 0) { sB2 = 4096; sk2 = 0u; }
  __syncthreads();
  if (k_rem > 0) {
    for (unsigned i = t; i < M; i += T)
      atomicAdd(&h2[(cand[i] >> 7) & 0xFFFu], 1u);
  }
  __syncthreads();
  unsigned cnt2[CH2];
  unsigned long long tot = 0;
  for (int j = 0; j < CH2; j++) { cnt2[j] = h2[t * CH2 + j]; tot += cnt2[j]; }
  sarr[t] = tot;
  __syncthreads();
  for (int off = 1; off < T; off <<= 1) {
    unsigned long long v = (t + off < T) ? sarr[t + off] : 0ull;
    __syncthreads();
    sarr[t] += v;
    __syncthreads();
  }
  if (k_rem > 0) {
    unsigned long long above = sarr[t] - tot;
    if (above < (unsigned long long)k_rem &&
        sarr[t] >= (unsigned long long)k_rem) {
      unsigned long long cum = above;
      for (int j = CH2 - 1; j >= 0; j--) {
        if (cum + (unsigned long long)cnt2[j] >= (unsigned long long)k_rem) {
          sB2 = t * CH2 + j;
          sk2 = (unsigned)((unsigned long long)k_rem - cum);
          break;
        }
        cum += cnt2[j];
      }
    }
  }
  __syncthreads();
  int B2 = sB2; unsigned k2r = sk2;
  double ssum = 0.0;
  if (k_rem > 0) {
    for (unsigned i = t; i < M; i += T) {
      unsigned bits = cand[i];
      int b2 = (int)((bits >> 7) & 0xFFFu);
      if (b2 > B2) ssum += (double)__uint_as_float(bits);
      else if (b2 == B2) atomicAdd(&h3[bits & 0x7Fu], 1u);
    }
  }
  for (int off = 32; off > 0; off >>= 1) ssum += __shfl_down(ssum, off);
  int wv = t >> 6, ln = t & 63;
  if (ln == 0) sws[wv] = ssum;
  __syncthreads();
  if (t == 0) {
    double sum2 = 0.0;
    for (int w = 0; w < T / 64; w++) sum2 += sws[w];
    double partial = 0.0;
    unsigned rem = k2r;
    unsigned base = (ctrl->B << 19) | ((unsigned)B2 << 7);
    for (int b = 127; b >= 0 && rem > 0; b--) {
      unsigned c = h3[b];
      if (!c) continue;
      unsigned take = (c < rem) ? c : rem;
      partial += (double)take * (double)__uint_as_float(base | (unsigned)b);
      rem -= take;
    }
    double neg_sum = ctrl->sum_above + sum2 + partial;
    double denom = (double)ctrl->pos_cnt + (double)ctrl->k + 1e-6;
    out[0] = (float)((ctrl->pos_sum + neg_sum) / denom);
  }
}

// ---------------------------------------------------------------------------
extern "C" void kernel_launch(void* const* d_in, const int* in_sizes, int n_in,
                              void* d_out, int out_size, void* d_ws, size_t ws_size,
                              hipStream_t stream) {
  const float* pred = (const float*)d_in[0];
  const float* gt   = (const float*)d_in[1];
  const float* mask = (const float*)d_in[2];
  float* out = (float*)d_out;
  int n = in_sizes[0];
  int n4 = n / 4;
  char* ws = (char*)d_ws;

  // fast-path layout: ctrl@0, hist1@256 (16KB), binsum@16640 (32KB),
  // h3@49408 (32B); neg16 @65536 (2n bytes).
  const size_t HIST1_OFF = 256;
  const size_t BINSUM_OFF = HIST1_OFF + NBINS1 * sizeof(unsigned);   // 16640
  const size_t H3_OFF = BINSUM_OFF + NBINS1 * sizeof(double);        // 49408
  const size_t ZERO_BYTES = H3_OFF + 8 * sizeof(unsigned);           // 49440
  const size_t NEG_OFF = 65536;
  size_t neg_bytes = (size_t)n * 2;
  size_t need = NEG_OFF + neg_bytes + 64;

  if (ws_size >= need) {
    Ctrl* ctrl = (Ctrl*)ws;
    unsigned* hist1 = (unsigned*)(ws + HIST1_OFF);
    double* binsum = (double*)(ws + BINSUM_OFF);
    unsigned* h3 = (unsigned*)(ws + H3_OFF);
    unsigned* neg16_2 = (unsigned*)(ws + NEG_OFF);
    unsigned short* neg16s = (unsigned short*)(ws + NEG_OFF);
    int n16 = n / 8;   // uint4 units of the u16 array

    const int CHUNK1 = Q_THREADS * 4;  // float4 slots
    const int CHUNK2 = Q_THREADS * 4;  // uint4 slots
    unsigned nchunks1 = (unsigned)((n4 + CHUNK1 - 1) / CHUNK1);
    unsigned nchunks2 = (unsigned)((n16 + CHUNK2 - 1) / CHUNK2);

    hipMemsetAsync(d_ws, 0, ZERO_BYTES, stream);
    q1_stream<<<Q_BLOCKS, Q_THREADS, 0, stream>>>(
        pred, gt, mask, neg16_2, neg16s, hist1, binsum, ctrl, n4, n, nchunks1);
    q2_scan<<<Q_BLOCKS, Q_THREADS, 0, stream>>>(
        (const uint4*)neg16_2, neg16s, ctrl, h3, out, n16, n, nchunks2);
  } else {
    // fallback: exact R2 pipeline
    Ctrl* ctrl = (Ctrl*)ws;
    unsigned* hist1 = (unsigned*)(ws + 256);
    size_t coff = 256 + (size_t)NBINS1 * sizeof(unsigned);
    unsigned* cand = (unsigned*)(ws + coff);
    unsigned cap = 0;
    if (ws_size > coff + 4) {
      size_t c = (ws_size - coff) / 4;
      cap = (c > (size_t)n) ? (unsigned)n : (unsigned)c;
    }
    hipMemsetAsync(d_ws, 0, coff, stream);
    k1_hist<<<K1_BLOCKS, 256, 0, stream>>>(pred, gt, mask, hist1, ctrl, n4, n);
    k2_select_fb<<<1, 256, 0, stream>>>(hist1, ctrl);
    int blocks3 = (n4 + K3_VEC_PER_BLOCK - 1) / K3_VEC_PER_BLOCK;
    if (blocks3 < 1) blocks3 = 1;
    k3_compact<<<blocks3, 256, 0, stream>>>(pred, gt, mask, ctrl, cand, cap, n4, n);
    k4_final<<<1, 1024, 0, stream>>>(cand, ctrl, out, cap);
  }
}

// Round 7
// 482.929 us; speedup vs baseline: 1.1420x; 1.1420x over previous
//
#include <hip/hip_runtime.h>
#include <math.h>

// MaskedBalancedBCELoss — hard-negative mining via histogram select.
//
// R7: SINGLE fused streaming kernel. Key approximation: the 13-bit boundary
// bin's contribution is binsum[B] * k_rem / cnt[B] (bin mean x taken count).
// Error <= k_rem * binwidth(2^-4 rel) ~ 3e-3 on output vs 4.75e-2 threshold.
// Everything else (counts, pos_sum, per-bin f64 sums) is near-exact.
//
//   Z1 (256 thr, grid 2048, ~24.7KB LDS -> 6 blocks/CU):
//     stream pred/gt/mask -> pos/neg counts, pos_sum,
//     LDS hist: packed-u16 counts (8KB) + f32 sums (16KB) over 4096 bins
//     (bin = float_bits(loss) >> 19); flush to global hist1/binsum;
//     LAST block (ticket): k = min(3*pos, neg), boundary bin B, k_rem,
//     neg_sum = sum_{b>B} binsum[b] + binsum[B]*k_rem/cnt[B]; write out.
// Fallback (tiny ws): proven exact R2 pipeline.

#define NBINS1 4096
#define Z_THREADS 256
#define Z_BLOCKS 2048
#define K1_BLOCKS 1024
#define K3_MAX_LOCAL 7168
#define K3_VEC_PER_BLOCK 1792

struct Ctrl {
  unsigned long long pos_cnt;
  unsigned long long neg_cnt;
  unsigned long long k;
  double pos_sum;
  double sum_above;
  unsigned B;
  unsigned k_rem;
  unsigned done1;
  unsigned cand_cnt;   // fallback only
};

#define LN2F 0.69314718055994530942f

__device__ __forceinline__ float neg_loss_from(float p) {
  return -fmaxf(__log2f(1.0f - p) * LN2F, -100.0f);
}
__device__ __forceinline__ float pos_loss_from(float p) {
  return -fmaxf(__log2f(p) * LN2F, -100.0f);
}

// ====================== FAST PATH: one kernel ==============================

extern "C" __global__ void __launch_bounds__(Z_THREADS)
z1_fused(const float* __restrict__ pred, const float* __restrict__ gt,
         const float* __restrict__ mask, unsigned* __restrict__ hist1,
         double* __restrict__ binsum, Ctrl* __restrict__ ctrl,
         float* __restrict__ out, int n4, int n) {
  __shared__ unsigned hcnt2[NBINS1 / 2];   // packed u16 counts, 8 KB
  __shared__ float    hsum[NBINS1];        // f32 sums, 16 KB (reused as sarr)
  __shared__ unsigned long long spc[4], snc[4];
  __shared__ double sps[4];
  __shared__ unsigned s_ticket;
  const int T = Z_THREADS;
  int tid = threadIdx.x;

  for (int i = tid; i < NBINS1 / 2; i += T) hcnt2[i] = 0u;
  for (int i = tid; i < NBINS1; i += T) hsum[i] = 0.0f;
  __syncthreads();

  unsigned pc = 0, nc = 0;
  double psum = 0.0;
  const float4* p4 = (const float4*)pred;
  const float4* g4 = (const float4*)gt;
  const float4* m4 = (const float4*)mask;

  int gtid = blockIdx.x * T + tid;
  int gstride = gridDim.x * T;
  for (int i = gtid; i < n4; i += gstride) {
    float4 pv = p4[i], gv = g4[i], mv = m4[i];
    float pa[4] = {pv.x, pv.y, pv.z, pv.w};
    float ga[4] = {gv.x, gv.y, gv.z, gv.w};
    float ma[4] = {mv.x, mv.y, mv.z, mv.w};
#pragma unroll
    for (int e = 0; e < 4; e++) {
      bool valid = (ma[e] != 0.0f);
      bool pos = valid & (ga[e] != 0.0f);
      bool neg = valid & (ga[e] == 0.0f);
      float x = neg ? (1.0f - pa[e]) : pa[e];
      float l = -fmaxf(__log2f(x) * LN2F, -100.0f);
      pc += pos ? 1u : 0u;
      nc += neg ? 1u : 0u;
      psum += pos ? (double)l : 0.0;
      if (neg) {
        unsigned b = __float_as_uint(l) >> 19;
        atomicAdd(&hcnt2[b >> 1], (b & 1u) ? 65536u : 1u);
        atomicAdd(&hsum[b], l);
      }
    }
  }
  // scalar tail (n % 4 != 0)
  for (int i = n4 * 4 + gtid; i < n; i += gstride) {
    float p = pred[i], g = gt[i], m = mask[i];
    bool valid = (m != 0.0f);
    bool pos = valid & (g != 0.0f);
    bool neg = valid & (g == 0.0f);
    float x = neg ? (1.0f - p) : p;
    float l = -fmaxf(__log2f(x) * LN2F, -100.0f);
    pc += pos ? 1u : 0u;
    nc += neg ? 1u : 0u;
    psum += pos ? (double)l : 0.0;
    if (neg) {
      unsigned b = __float_as_uint(l) >> 19;
      atomicAdd(&hcnt2[b >> 1], (b & 1u) ? 65536u : 1u);
      atomicAdd(&hsum[b], l);
    }
  }

  // block reduce pc/nc/psum
  unsigned long long pcl = pc, ncl = nc;
  for (int off = 32; off > 0; off >>= 1) {
    pcl += __shfl_down(pcl, off);
    ncl += __shfl_down(ncl, off);
    psum += __shfl_down(psum, off);
  }
  int wv = tid >> 6, ln = tid & 63;
  if (ln == 0) { spc[wv] = pcl; snc[wv] = ncl; sps[wv] = psum; }
  __syncthreads();   // also completes all LDS hist atomics
  if (tid == 0) {
    unsigned long long tp = 0, tn = 0; double ts = 0.0;
    for (int w = 0; w < 4; w++) { tp += spc[w]; tn += snc[w]; ts += sps[w]; }
    atomicAdd(&ctrl->pos_cnt, tp);
    atomicAdd(&ctrl->neg_cnt, tn);
    unsafeAtomicAdd(&ctrl->pos_sum, ts);
  }
  // flush histograms to global
  for (int i = tid; i < NBINS1 / 2; i += T) {
    unsigned w = hcnt2[i];
    unsigned lo = w & 0xFFFFu, hi = w >> 16;
    if (lo) atomicAdd(&hist1[2 * i], lo);
    if (hi) atomicAdd(&hist1[2 * i + 1], hi);
  }
  for (int b = tid; b < NBINS1; b += T) {
    float s = hsum[b];
    if (s != 0.0f) unsafeAtomicAdd(&binsum[b], (double)s);
  }
  __syncthreads();
  __threadfence();
  if (tid == 0) s_ticket = atomicAdd(&ctrl->done1, 1u);
  __syncthreads();
  if (s_ticket != (unsigned)(gridDim.x - 1)) return;
  __threadfence();   // acquire: all blocks' atomics visible

  // ---------------- last block: select + finalize ----------------
  const int CH = NBINS1 / T;  // 16 bins per thread
  unsigned long long* sarr = (unsigned long long*)hsum;  // reuse LDS (2KB)
  double* sred = sps;                                    // reuse
  __shared__ unsigned long long sk;
  __shared__ unsigned sB, skrem;
  int t = tid;

  unsigned cnt[CH];
  unsigned long long tot = 0;
  for (int j = 0; j < CH; j++) { cnt[j] = hist1[t * CH + j]; tot += cnt[j]; }
  __syncthreads();   // hsum flush reads long done; safe to overwrite
  sarr[t] = tot;
  if (t == 0) {
    sB = 0xFFFFFFFFu; skrem = 0u;
    unsigned long long pos = ctrl->pos_cnt, negtot = ctrl->neg_cnt;
    unsigned long long k = 0;
    if (pos > 0) {               // FALLBACK_NEG=0 when pos==0
      k = pos * 3ull;            // floor(pos*3.0), exact in integer
      if (k > negtot) k = negtot;
    }
    ctrl->k = k;
    sk = k;
  }
  __syncthreads();
  // inclusive suffix scan: sarr[t] = sum_{u>=t}
  for (int off = 1; off < T; off <<= 1) {
    unsigned long long v = (t + off < T) ? sarr[t + off] : 0ull;
    __syncthreads();
    sarr[t] += v;
    __syncthreads();
  }
  unsigned long long k = sk;
  if (k > 0) {
    unsigned long long above = sarr[t] - tot;
    if (above < k && sarr[t] >= k) {
      unsigned long long cum = above;
      for (int j = CH - 1; j >= 0; j--) {
        if (cum + (unsigned long long)cnt[j] >= k) {
          sB = (unsigned)(t * CH + j);
          skrem = (unsigned)(k - cum);
          break;
        }
        cum += cnt[j];
      }
    }
  }
  __syncthreads();
  unsigned B = sB;

  // sum_above = sum of binsum[b] for b > B
  double s = 0.0;
  if (B != 0xFFFFFFFFu) {
    for (int bi = t; bi < NBINS1; bi += T)
      if (bi > (int)B) s += binsum[bi];
  }
  for (int off = 32; off > 0; off >>= 1) s += __shfl_down(s, off);
  if (ln == 0) sred[wv] = s;
  __syncthreads();
  if (t == 0) {
    double sum_above = sred[0] + sred[1] + sred[2] + sred[3];
    double partial = 0.0;
    if (skrem > 0 && B != 0xFFFFFFFFu) {
      unsigned cb = hist1[B];
      if (cb) partial = binsum[B] * ((double)skrem / (double)cb);
    }
    double neg_sum = sum_above + partial;
    double denom = (double)ctrl->pos_cnt + (double)k + 1e-6;
    out[0] = (float)((ctrl->pos_sum + neg_sum) / denom);
  }
}

// ====================== FALLBACK (proven R2 exact pipeline) ================

extern "C" __global__ void __launch_bounds__(256)
k1_hist(const float* __restrict__ pred, const float* __restrict__ gt,
        const float* __restrict__ mask, unsigned* __restrict__ hist1,
        Ctrl* __restrict__ ctrl, int n4, int n) {
  __shared__ unsigned h[NBINS1];
  for (int i = threadIdx.x; i < NBINS1; i += blockDim.x) h[i] = 0u;
  __syncthreads();
  unsigned pc = 0, nc = 0;
  double psum = 0.0;
  const float4* p4 = (const float4*)pred;
  const float4* g4 = (const float4*)gt;
  const float4* m4 = (const float4*)mask;
  int gtid = blockIdx.x * blockDim.x + threadIdx.x;
  int stride = gridDim.x * blockDim.x;
  for (int i = gtid; i < n4; i += stride) {
    float4 pv = p4[i], gv = g4[i], mv = m4[i];
    float pa[4] = {pv.x, pv.y, pv.z, pv.w};
    float ga[4] = {gv.x, gv.y, gv.z, gv.w};
    float ma[4] = {mv.x, mv.y, mv.z, mv.w};
#pragma unroll
    for (int j = 0; j < 4; j++) {
      if (ma[j] != 0.0f) {
        if (ga[j] != 0.0f) { pc++; psum += (double)pos_loss_from(pa[j]); }
        else {
          nc++;
          atomicAdd(&h[__float_as_uint(neg_loss_from(pa[j])) >> 19], 1u);
        }
      }
    }
  }
  for (int i = n4 * 4 + gtid; i < n; i += stride) {
    float p = pred[i], g = gt[i], m = mask[i];
    if (m != 0.0f) {
      if (g != 0.0f) { pc++; psum += (double)pos_loss_from(p); }
      else { nc++; atomicAdd(&h[__float_as_uint(neg_loss_from(p)) >> 19], 1u); }
    }
  }
  unsigned long long pcl = pc, ncl = nc;
  for (int off = 32; off > 0; off >>= 1) {
    pcl += __shfl_down(pcl, off);
    ncl += __shfl_down(ncl, off);
    psum += __shfl_down(psum, off);
  }
  __shared__ unsigned long long spc[4], snc[4];
  __shared__ double sps[4];
  int wv = threadIdx.x >> 6, ln = threadIdx.x & 63;
  if (ln == 0) { spc[wv] = pcl; snc[wv] = ncl; sps[wv] = psum; }
  __syncthreads();
  if (threadIdx.x == 0) {
    unsigned long long tp = 0, tn = 0; double ts = 0.0;
    for (int w = 0; w < 4; w++) { tp += spc[w]; tn += snc[w]; ts += sps[w]; }
    atomicAdd(&ctrl->pos_cnt, tp);
    atomicAdd(&ctrl->neg_cnt, tn);
    unsafeAtomicAdd(&ctrl->pos_sum, ts);
  }
  for (int i = threadIdx.x; i < NBINS1; i += blockDim.x) {
    unsigned c = h[i];
    if (c) atomicAdd(&hist1[i], c);
  }
}

extern "C" __global__ void __launch_bounds__(256)
k2_select_fb(const unsigned* __restrict__ hist1, Ctrl* __restrict__ ctrl) {
  const int T = 256, CH = NBINS1 / T;
  __shared__ unsigned long long sarr[T];
  __shared__ unsigned long long sk;
  int t = threadIdx.x;
  unsigned cnt[CH];
  unsigned long long tot = 0;
  for (int j = 0; j < CH; j++) { cnt[j] = hist1[t * CH + j]; tot += cnt[j]; }
  sarr[t] = tot;
  __syncthreads();
  for (int off = 1; off < T; off <<= 1) {
    unsigned long long v = (t + off < T) ? sarr[t + off] : 0ull;
    __syncthreads();
    sarr[t] += v;
    __syncthreads();
  }
  if (t == 0) {
    unsigned long long pos = ctrl->pos_cnt, negtot = ctrl->neg_cnt;
    unsigned long long k = 0;
    if (pos > 0) {
      k = pos * 3ull;
      if (k > negtot) k = negtot;
    }
    ctrl->k = k;
    sk = k;
    if (k == 0) { ctrl->B = 0xFFFFFFFFu; ctrl->k_rem = 0u; }
  }
  __syncthreads();
  unsigned long long k = sk;
  if (k > 0) {
    unsigned long long above = sarr[t] - tot;
    if (above < k && sarr[t] >= k) {
      unsigned long long cum = above;
      for (int j = CH - 1; j >= 0; j--) {
        if (cum + (unsigned long long)cnt[j] >= k) {
          ctrl->B = (unsigned)(t * CH + j);
          ctrl->k_rem = (unsigned)(k - cum);
          break;
        }
        cum += cnt[j];
      }
    }
  }
}

extern "C" __global__ void __launch_bounds__(256)
k3_compact(const float* __restrict__ pred, const float* __restrict__ gt,
           const float* __restrict__ mask, Ctrl* __restrict__ ctrl,
           unsigned* __restrict__ cand, unsigned cap, int n4, int n) {
  __shared__ unsigned lbuf[K3_MAX_LOCAL];
  __shared__ unsigned lcnt;
  __shared__ unsigned gbase;
  __shared__ double sws[4];
  if (threadIdx.x == 0) { lcnt = 0u; gbase = 0u; }
  __syncthreads();
  const unsigned B = ctrl->B;
  double ssum = 0.0;
  const float4* p4 = (const float4*)pred;
  const float4* g4 = (const float4*)gt;
  const float4* m4 = (const float4*)mask;
  int gtid = blockIdx.x * blockDim.x + threadIdx.x;
  int stride = gridDim.x * blockDim.x;
  for (int i = gtid; i < n4; i += stride) {
    float4 pv = p4[i], gv = g4[i], mv = m4[i];
    float pa[4] = {pv.x, pv.y, pv.z, pv.w};
    float ga[4] = {gv.x, gv.y, gv.z, gv.w};
    float ma[4] = {mv.x, mv.y, mv.z, mv.w};
#pragma unroll
    for (int j = 0; j < 4; j++) {
      if (ma[j] != 0.0f && ga[j] == 0.0f) {
        float loss = neg_loss_from(pa[j]);
        unsigned bits = __float_as_uint(loss);
        unsigned b = bits >> 19;
        if (B != 0xFFFFFFFFu && b > B) ssum += (double)loss;
        else if (b == B) {
          unsigned idx = atomicAdd(&lcnt, 1u);
          if (idx < K3_MAX_LOCAL) lbuf[idx] = bits;
        }
      }
    }
  }
  for (int i = n4 * 4 + gtid; i < n; i += stride) {
    float p = pred[i], g = gt[i], m = mask[i];
    if (m != 0.0f && g == 0.0f) {
      float loss = neg_loss_from(p);
      unsigned bits = __float_as_uint(loss);
      unsigned b = bits >> 19;
      if (B != 0xFFFFFFFFu && b > B) ssum += (double)loss;
      else if (b == B) {
        unsigned idx = atomicAdd(&lcnt, 1u);
        if (idx < K3_MAX_LOCAL) lbuf[idx] = bits;
      }
    }
  }
  for (int off = 32; off > 0; off >>= 1) ssum += __shfl_down(ssum, off);
  int wv = threadIdx.x >> 6, ln = threadIdx.x & 63;
  if (ln == 0) sws[wv] = ssum;
  __syncthreads();
  if (threadIdx.x == 0) {
    unsafeAtomicAdd(&ctrl->sum_above, sws[0] + sws[1] + sws[2] + sws[3]);
    unsigned c = lcnt;
    if (c > K3_MAX_LOCAL) c = K3_MAX_LOCAL;
    lcnt = c;
    gbase = c ? atomicAdd(&ctrl->cand_cnt, c) : 0u;
  }
  __syncthreads();
  unsigned c = lcnt, base = gbase;
  for (unsigned i = threadIdx.x; i < c; i += blockDim.x) {
    unsigned dst = base + i;
    if (dst < cap) cand[dst] = lbuf[i];
  }
}

extern "C" __global__ void __launch_bounds__(1024)
k4_final(const unsigned* __restrict__ cand, Ctrl* __restrict__ ctrl,
         float* __restrict__ out, unsigned cap) {
  const int T = 1024, CH2 = 4096 / T;
  __shared__ unsigned h2[4096];
  __shared__ unsigned h3[128];
  __shared__ unsigned long long sarr[T];
  __shared__ int sB2;
  __shared__ unsigned sk2;
  __shared__ double sws[16];
  int t = threadIdx.x;
  unsigned M = ctrl->cand_cnt; if (M > cap) M = cap;
  unsigned k_rem = ctrl->k_rem;
  for (int i = t; i < 4096; i += T) h2[i] = 0u;
  for (int i = t; i < 128; i += T) h3[i] = 0u;
  if (t == 0) { sB2 = 4096; sk2 = 0u; }
  __syncthreads();
  if (k_rem > 0) {
    for (unsigned i = t; i < M; i += T)
      atomicAdd(&h2[(cand[i] >> 7) & 0xFFFu], 1u);
  }
  __syncthreads();
  unsigned cnt2[CH2];
  unsigned long long tot = 0;
  for (int j = 0; j < CH2; j++) { cnt2[j] = h2[t * CH2 + j]; tot += cnt2[j]; }
  sarr[t] = tot;
  __syncthreads();
  for (int off = 1; off < T; off <<= 1) {
    unsigned long long v = (t + off < T) ? sarr[t + off] : 0ull;
    __syncthreads();
    sarr[t] += v;
    __syncthreads();
  }
  if (k_rem > 0) {
    unsigned long long above = sarr[t] - tot;
    if (above < (unsigned long long)k_rem &&
        sarr[t] >= (unsigned long long)k_rem) {
      unsigned long long cum = above;
      for (int j = CH2 - 1; j >= 0; j--) {
        if (cum + (unsigned long long)cnt2[j] >= (unsigned long long)k_rem) {
          sB2 = t * CH2 + j;
          sk2 = (unsigned)((unsigned long long)k_rem - cum);
          break;
        }
        cum += cnt2[j];
      }
    }
  }
  __syncthreads();
  int B2 = sB2; unsigned k2r = sk2;
  double ssum = 0.0;
  if (k_rem > 0) {
    for (unsigned i = t; i < M; i += T) {
      unsigned bits = cand[i];
      int b2 = (int)((bits >> 7) & 0xFFFu);
      if (b2 > B2) ssum += (double)__uint_as_float(bits);
      else if (b2 == B2) atomicAdd(&h3[bits & 0x7Fu], 1u);
    }
  }
  for (int off = 32; off > 0; off >>= 1) ssum += __shfl_down(ssum, off);
  int wv = t >> 6, ln = t & 63;
  if (ln == 0) sws[wv] = ssum;
  __syncthreads();
  if (t == 0) {
    double sum2 = 0.0;
    for (int w = 0; w < T / 64; w++) sum2 += sws[w];
    double partial = 0.0;
    unsigned rem = k2r;
    unsigned base = (ctrl->B << 19) | ((unsigned)B2 << 7);
    for (int b = 127; b >= 0 && rem > 0; b--) {
      unsigned c = h3[b];
      if (!c) continue;
      unsigned take = (c < rem) ? c : rem;
      partial += (double)take * (double)__uint_as_float(base | (unsigned)b);
      rem -= take;
    }
    double neg_sum = ctrl->sum_above + sum2 + partial;
    double denom = (double)ctrl->pos_cnt + (double)ctrl->k + 1e-6;
    out[0] = (float)((ctrl->pos_sum + neg_sum) / denom);
  }
}

// ---------------------------------------------------------------------------
extern "C" void kernel_launch(void* const* d_in, const int* in_sizes, int n_in,
                              void* d_out, int out_size, void* d_ws, size_t ws_size,
                              hipStream_t stream) {
  const float* pred = (const float*)d_in[0];
  const float* gt   = (const float*)d_in[1];
  const float* mask = (const float*)d_in[2];
  float* out = (float*)d_out;
  int n = in_sizes[0];
  int n4 = n / 4;
  char* ws = (char*)d_ws;

  // layout: ctrl@0, hist1@256 (16KB), binsum@16640 (32KB) -> zero 49408 B
  const size_t HIST1_OFF = 256;
  const size_t BINSUM_OFF = HIST1_OFF + NBINS1 * sizeof(unsigned);   // 16640
  const size_t ZERO_BYTES = BINSUM_OFF + NBINS1 * sizeof(double);    // 49408

  if (ws_size >= 65536) {
    Ctrl* ctrl = (Ctrl*)ws;
    unsigned* hist1 = (unsigned*)(ws + HIST1_OFF);
    double* binsum = (double*)(ws + BINSUM_OFF);
    hipMemsetAsync(d_ws, 0, ZERO_BYTES, stream);
    z1_fused<<<Z_BLOCKS, Z_THREADS, 0, stream>>>(pred, gt, mask, hist1,
                                                 binsum, ctrl, out, n4, n);
  } else {
    // fallback: exact R2 pipeline (needs cand space)
    Ctrl* ctrl = (Ctrl*)ws;
    unsigned* hist1 = (unsigned*)(ws + 256);
    size_t coff = 256 + (size_t)NBINS1 * sizeof(unsigned);
    unsigned* cand = (unsigned*)(ws + coff);
    unsigned cap = 0;
    if (ws_size > coff + 4) {
      size_t c = (ws_size - coff) / 4;
      cap = (c > (size_t)n) ? (unsigned)n : (unsigned)c;
    }
    hipMemsetAsync(d_ws, 0, coff, stream);
    k1_hist<<<K1_BLOCKS, 256, 0, stream>>>(pred, gt, mask, hist1, ctrl, n4, n);
    k2_select_fb<<<1, 256, 0, stream>>>(hist1, ctrl);
    int blocks3 = (n4 + K3_VEC_PER_BLOCK - 1) / K3_VEC_PER_BLOCK;
    if (blocks3 < 1) blocks3 = 1;
    k3_compact<<<blocks3, 256, 0, stream>>>(pred, gt, mask, ctrl, cand, cap, n4, n);
    k4_final<<<1, 1024, 0, stream>>>(cand, ctrl, out, cap);
  }
}

// Round 8
// 250.293 us; speedup vs baseline: 2.2034x; 1.9294x over previous
//
#include <hip/hip_runtime.h>
#include <math.h>

// MaskedBalancedBCELoss — hard-negative mining via count-histogram select.
//
// R8: single fused kernel, COUNTS-ONLY histogram (the proven-77µs R2-k1 hot
// loop). neg_sum is reconstructed from bin counts x bin midpoints:
//   bin b = float_bits(loss) >> 19  (13-bit: exp + 4 mantissa bits)
//   mid(b) = as_float((b<<19) | 0x40000)   — exact value-space midpoint
//   neg_sum ~= sum_{b>B} cnt[b]*mid(b) + k_rem*mid(B)
// Rel half-width 2^-5; smooth loss distribution => within-bin mean ~ midpoint;
// expected output error ~1e-3 vs threshold 4.75e-2. No float LDS atomics
// (R7's 390µs was the shared-float atomicAdd CAS loop + packed-count
// contention), no negbits array, no second pass.
//
//   Y1 (256 thr, grid 1024, 16KB LDS): stream pred/gt/mask ->
//     pos/neg counts, pos_sum (f64), LDS u32 count hist (4096 bins) ->
//     global hist1; LAST block (ticket): k = min(3*pos, neg), boundary bin B,
//     k_rem, neg_sum from midpoints, write out.
// Fallback (tiny ws): proven exact R2 pipeline.

#define NBINS1 4096
#define Y_THREADS 256
#define Y_BLOCKS 1024
#define K1_BLOCKS 1024
#define K3_MAX_LOCAL 7168
#define K3_VEC_PER_BLOCK 1792

struct Ctrl {
  unsigned long long pos_cnt;
  unsigned long long neg_cnt;
  unsigned long long k;
  double pos_sum;
  double sum_above;
  unsigned B;
  unsigned k_rem;
  unsigned done1;
  unsigned cand_cnt;   // fallback only
};

#define LN2F 0.69314718055994530942f

__device__ __forceinline__ float neg_loss_from(float p) {
  return -fmaxf(__log2f(1.0f - p) * LN2F, -100.0f);
}
__device__ __forceinline__ float pos_loss_from(float p) {
  return -fmaxf(__log2f(p) * LN2F, -100.0f);
}

__device__ __forceinline__ double bin_mid(unsigned b) {
  return (double)__uint_as_float((b << 19) | 0x40000u);
}

// ====================== FAST PATH: one kernel ==============================

extern "C" __global__ void __launch_bounds__(Y_THREADS)
y1_fused(const float* __restrict__ pred, const float* __restrict__ gt,
         const float* __restrict__ mask, unsigned* __restrict__ hist1,
         Ctrl* __restrict__ ctrl, float* __restrict__ out, int n4, int n) {
  __shared__ unsigned h[NBINS1];       // 16 KB u32 counts (reused as sarr)
  __shared__ unsigned long long spc[4], snc[4];
  __shared__ double sps[4];
  __shared__ unsigned s_ticket;
  const int T = Y_THREADS;
  int tid = threadIdx.x;

  for (int i = tid; i < NBINS1; i += T) h[i] = 0u;
  __syncthreads();

  unsigned pc = 0, nc = 0;
  double psum = 0.0;
  const float4* p4 = (const float4*)pred;
  const float4* g4 = (const float4*)gt;
  const float4* m4 = (const float4*)mask;

  int gtid = blockIdx.x * T + tid;
  int gstride = gridDim.x * T;
  for (int i = gtid; i < n4; i += gstride) {
    float4 pv = p4[i], gv = g4[i], mv = m4[i];
    float pa[4] = {pv.x, pv.y, pv.z, pv.w};
    float ga[4] = {gv.x, gv.y, gv.z, gv.w};
    float ma[4] = {mv.x, mv.y, mv.z, mv.w};
#pragma unroll
    for (int e = 0; e < 4; e++) {
      bool valid = (ma[e] != 0.0f);
      bool pos = valid & (ga[e] != 0.0f);
      bool neg = valid & (ga[e] == 0.0f);
      float x = neg ? (1.0f - pa[e]) : pa[e];
      float l = -fmaxf(__log2f(x) * LN2F, -100.0f);
      pc += pos ? 1u : 0u;
      nc += neg ? 1u : 0u;
      psum += pos ? (double)l : 0.0;
      if (neg) atomicAdd(&h[__float_as_uint(l) >> 19], 1u);
    }
  }
  // scalar tail (n % 4 != 0)
  for (int i = n4 * 4 + gtid; i < n; i += gstride) {
    float p = pred[i], g = gt[i], m = mask[i];
    bool valid = (m != 0.0f);
    bool pos = valid & (g != 0.0f);
    bool neg = valid & (g == 0.0f);
    float x = neg ? (1.0f - p) : p;
    float l = -fmaxf(__log2f(x) * LN2F, -100.0f);
    pc += pos ? 1u : 0u;
    nc += neg ? 1u : 0u;
    psum += pos ? (double)l : 0.0;
    if (neg) atomicAdd(&h[__float_as_uint(l) >> 19], 1u);
  }

  // block reduce pc/nc/psum
  unsigned long long pcl = pc, ncl = nc;
  for (int off = 32; off > 0; off >>= 1) {
    pcl += __shfl_down(pcl, off);
    ncl += __shfl_down(ncl, off);
    psum += __shfl_down(psum, off);
  }
  int wv = tid >> 6, ln = tid & 63;
  if (ln == 0) { spc[wv] = pcl; snc[wv] = ncl; sps[wv] = psum; }
  __syncthreads();   // also completes all LDS hist atomics
  if (tid == 0) {
    unsigned long long tp = 0, tn = 0; double ts = 0.0;
    for (int w = 0; w < 4; w++) { tp += spc[w]; tn += snc[w]; ts += sps[w]; }
    atomicAdd(&ctrl->pos_cnt, tp);
    atomicAdd(&ctrl->neg_cnt, tn);
    unsafeAtomicAdd(&ctrl->pos_sum, ts);
  }
  // flush non-empty bins to global
  for (int i = tid; i < NBINS1; i += T) {
    unsigned c = h[i];
    if (c) atomicAdd(&hist1[i], c);
  }
  __syncthreads();
  __threadfence();
  if (tid == 0) s_ticket = atomicAdd(&ctrl->done1, 1u);
  __syncthreads();
  if (s_ticket != (unsigned)(gridDim.x - 1)) return;
  __threadfence();   // acquire: all blocks' atomics visible

  // ---------------- last block: select + finalize ----------------
  const int CH = NBINS1 / T;  // 16 bins per thread
  unsigned long long* sarr = (unsigned long long*)h;  // reuse LDS (2KB)
  double* sred = sps;
  __shared__ unsigned long long sk;
  __shared__ unsigned sB, skrem;
  int t = tid;

  unsigned cnt[CH];
  unsigned long long tot = 0;
  for (int j = 0; j < CH; j++) { cnt[j] = hist1[t * CH + j]; tot += cnt[j]; }
  __syncthreads();   // h flush reads long done; safe to overwrite
  sarr[t] = tot;
  if (t == 0) {
    sB = 0xFFFFFFFFu; skrem = 0u;
    unsigned long long pos = ctrl->pos_cnt, negtot = ctrl->neg_cnt;
    unsigned long long k = 0;
    if (pos > 0) {               // FALLBACK_NEG=0 when pos==0
      k = pos * 3ull;            // floor(pos*3.0), exact in integer
      if (k > negtot) k = negtot;
    }
    ctrl->k = k;
    sk = k;
  }
  __syncthreads();
  // inclusive suffix scan: sarr[t] = sum over threads >= t
  for (int off = 1; off < T; off <<= 1) {
    unsigned long long v = (t + off < T) ? sarr[t + off] : 0ull;
    __syncthreads();
    sarr[t] += v;
    __syncthreads();
  }
  unsigned long long k = sk;
  if (k > 0) {
    unsigned long long above = sarr[t] - tot;
    if (above < k && sarr[t] >= k) {
      unsigned long long cum = above;
      for (int j = CH - 1; j >= 0; j--) {
        if (cum + (unsigned long long)cnt[j] >= k) {
          sB = (unsigned)(t * CH + j);
          skrem = (unsigned)(k - cum);
          break;
        }
        cum += cnt[j];
      }
    }
  }
  __syncthreads();
  unsigned B = sB;

  // neg_sum (midpoint model): each thread sums its own bins above B
  double s = 0.0;
  if (B != 0xFFFFFFFFu) {
    for (int j = 0; j < CH; j++) {
      unsigned bi = (unsigned)(t * CH + j);
      if (bi > B && cnt[j]) s += (double)cnt[j] * bin_mid(bi);
    }
  }
  for (int off = 32; off > 0; off >>= 1) s += __shfl_down(s, off);
  if (ln == 0) sred[wv] = s;
  __syncthreads();
  if (t == 0) {
    double neg_sum = sred[0] + sred[1] + sred[2] + sred[3];
    if (skrem > 0 && B != 0xFFFFFFFFu)
      neg_sum += (double)skrem * bin_mid(B);
    double denom = (double)ctrl->pos_cnt + (double)k + 1e-6;
    out[0] = (float)((ctrl->pos_sum + neg_sum) / denom);
  }
}

// ====================== FALLBACK (proven R2 exact pipeline) ================

extern "C" __global__ void __launch_bounds__(256)
k1_hist(const float* __restrict__ pred, const float* __restrict__ gt,
        const float* __restrict__ mask, unsigned* __restrict__ hist1,
        Ctrl* __restrict__ ctrl, int n4, int n) {
  __shared__ unsigned h[NBINS1];
  for (int i = threadIdx.x; i < NBINS1; i += blockDim.x) h[i] = 0u;
  __syncthreads();
  unsigned pc = 0, nc = 0;
  double psum = 0.0;
  const float4* p4 = (const float4*)pred;
  const float4* g4 = (const float4*)gt;
  const float4* m4 = (const float4*)mask;
  int gtid = blockIdx.x * blockDim.x + threadIdx.x;
  int stride = gridDim.x * blockDim.x;
  for (int i = gtid; i < n4; i += stride) {
    float4 pv = p4[i], gv = g4[i], mv = m4[i];
    float pa[4] = {pv.x, pv.y, pv.z, pv.w};
    float ga[4] = {gv.x, gv.y, gv.z, gv.w};
    float ma[4] = {mv.x, mv.y, mv.z, mv.w};
#pragma unroll
    for (int j = 0; j < 4; j++) {
      if (ma[j] != 0.0f) {
        if (ga[j] != 0.0f) { pc++; psum += (double)pos_loss_from(pa[j]); }
        else {
          nc++;
          atomicAdd(&h[__float_as_uint(neg_loss_from(pa[j])) >> 19], 1u);
        }
      }
    }
  }
  for (int i = n4 * 4 + gtid; i < n; i += stride) {
    float p = pred[i], g = gt[i], m = mask[i];
    if (m != 0.0f) {
      if (g != 0.0f) { pc++; psum += (double)pos_loss_from(p); }
      else { nc++; atomicAdd(&h[__float_as_uint(neg_loss_from(p)) >> 19], 1u); }
    }
  }
  unsigned long long pcl = pc, ncl = nc;
  for (int off = 32; off > 0; off >>= 1) {
    pcl += __shfl_down(pcl, off);
    ncl += __shfl_down(ncl, off);
    psum += __shfl_down(psum, off);
  }
  __shared__ unsigned long long spc[4], snc[4];
  __shared__ double sps[4];
  int wv = threadIdx.x >> 6, ln = threadIdx.x & 63;
  if (ln == 0) { spc[wv] = pcl; snc[wv] = ncl; sps[wv] = psum; }
  __syncthreads();
  if (threadIdx.x == 0) {
    unsigned long long tp = 0, tn = 0; double ts = 0.0;
    for (int w = 0; w < 4; w++) { tp += spc[w]; tn += snc[w]; ts += sps[w]; }
    atomicAdd(&ctrl->pos_cnt, tp);
    atomicAdd(&ctrl->neg_cnt, tn);
    unsafeAtomicAdd(&ctrl->pos_sum, ts);
  }
  for (int i = threadIdx.x; i < NBINS1; i += blockDim.x) {
    unsigned c = h[i];
    if (c) atomicAdd(&hist1[i], c);
  }
}

extern "C" __global__ void __launch_bounds__(256)
k2_select_fb(const unsigned* __restrict__ hist1, Ctrl* __restrict__ ctrl) {
  const int T = 256, CH = NBINS1 / T;
  __shared__ unsigned long long sarr[T];
  __shared__ unsigned long long sk;
  int t = threadIdx.x;
  unsigned cnt[CH];
  unsigned long long tot = 0;
  for (int j = 0; j < CH; j++) { cnt[j] = hist1[t * CH + j]; tot += cnt[j]; }
  sarr[t] = tot;
  __syncthreads();
  for (int off = 1; off < T; off <<= 1) {
    unsigned long long v = (t + off < T) ? sarr[t + off] : 0ull;
    __syncthreads();
    sarr[t] += v;
    __syncthreads();
  }
  if (t == 0) {
    unsigned long long pos = ctrl->pos_cnt, negtot = ctrl->neg_cnt;
    unsigned long long k = 0;
    if (pos > 0) {
      k = pos * 3ull;
      if (k > negtot) k = negtot;
    }
    ctrl->k = k;
    sk = k;
    if (k == 0) { ctrl->B = 0xFFFFFFFFu; ctrl->k_rem = 0u; }
  }
  __syncthreads();
  unsigned long long k = sk;
  if (k > 0) {
    unsigned long long above = sarr[t] - tot;
    if (above < k && sarr[t] >= k) {
      unsigned long long cum = above;
      for (int j = CH - 1; j >= 0; j--) {
        if (cum + (unsigned long long)cnt[j] >= k) {
          ctrl->B = (unsigned)(t * CH + j);
          ctrl->k_rem = (unsigned)(k - cum);
          break;
        }
        cum += cnt[j];
      }
    }
  }
}

extern "C" __global__ void __launch_bounds__(256)
k3_compact(const float* __restrict__ pred, const float* __restrict__ gt,
           const float* __restrict__ mask, Ctrl* __restrict__ ctrl,
           unsigned* __restrict__ cand, unsigned cap, int n4, int n) {
  __shared__ unsigned lbuf[K3_MAX_LOCAL];
  __shared__ unsigned lcnt;
  __shared__ unsigned gbase;
  __shared__ double sws[4];
  if (threadIdx.x == 0) { lcnt = 0u; gbase = 0u; }
  __syncthreads();
  const unsigned B = ctrl->B;
  double ssum = 0.0;
  const float4* p4 = (const float4*)pred;
  const float4* g4 = (const float4*)gt;
  const float4* m4 = (const float4*)mask;
  int gtid = blockIdx.x * blockDim.x + threadIdx.x;
  int stride = gridDim.x * blockDim.x;
  for (int i = gtid; i < n4; i += stride) {
    float4 pv = p4[i], gv = g4[i], mv = m4[i];
    float pa[4] = {pv.x, pv.y, pv.z, pv.w};
    float ga[4] = {gv.x, gv.y, gv.z, gv.w};
    float ma[4] = {mv.x, mv.y, mv.z, mv.w};
#pragma unroll
    for (int j = 0; j < 4; j++) {
      if (ma[j] != 0.0f && ga[j] == 0.0f) {
        float loss = neg_loss_from(pa[j]);
        unsigned bits = __float_as_uint(loss);
        unsigned b = bits >> 19;
        if (B != 0xFFFFFFFFu && b > B) ssum += (double)loss;
        else if (b == B) {
          unsigned idx = atomicAdd(&lcnt, 1u);
          if (idx < K3_MAX_LOCAL) lbuf[idx] = bits;
        }
      }
    }
  }
  for (int i = n4 * 4 + gtid; i < n; i += stride) {
    float p = pred[i], g = gt[i], m = mask[i];
    if (m != 0.0f && g == 0.0f) {
      float loss = neg_loss_from(p);
      unsigned bits = __float_as_uint(loss);
      unsigned b = bits >> 19;
      if (B != 0xFFFFFFFFu && b > B) ssum += (double)loss;
      else if (b == B) {
        unsigned idx = atomicAdd(&lcnt, 1u);
        if (idx < K3_MAX_LOCAL) lbuf[idx] = bits;
      }
    }
  }
  for (int off = 32; off > 0; off >>= 1) ssum += __shfl_down(ssum, off);
  int wv = threadIdx.x >> 6, ln = threadIdx.x & 63;
  if (ln == 0) sws[wv] = ssum;
  __syncthreads();
  if (threadIdx.x == 0) {
    unsafeAtomicAdd(&ctrl->sum_above, sws[0] + sws[1] + sws[2] + sws[3]);
    unsigned c = lcnt;
    if (c > K3_MAX_LOCAL) c = K3_MAX_LOCAL;
    lcnt = c;
    gbase = c ? atomicAdd(&ctrl->cand_cnt, c) : 0u;
  }
  __syncthreads();
  unsigned c = lcnt, base = gbase;
  for (unsigned i = threadIdx.x; i < c; i += blockDim.x) {
    unsigned dst = base + i;
    if (dst < cap) cand[dst] = lbuf[i];
  }
}

extern "C" __global__ void __launch_bounds__(1024)
k4_final(const unsigned* __restrict__ cand, Ctrl* __restrict__ ctrl,
         float* __restrict__ out, unsigned cap) {
  const int T = 1024, CH2 = 4096 / T;
  __shared__ unsigned h2[4096];
  __shared__ unsigned h3[128];
  __shared__ unsigned long long sarr[T];
  __shared__ int sB2;
  __shared__ unsigned sk2;
  __shared__ double sws[16];
  int t = threadIdx.x;
  unsigned M = ctrl->cand_cnt; if (M > cap) M = cap;
  unsigned k_rem = ctrl->k_rem;
  for (int i = t; i < 4096; i += T) h2[i] = 0u;
  for (int i = t; i < 128; i += T) h3[i] = 0u;
  if (t == 0) { sB2 = 4096; sk2 = 0u; }
  __syncthreads();
  if (k_rem > 0) {
    for (unsigned i = t; i < M; i += T)
      atomicAdd(&h2[(cand[i] >> 7) & 0xFFFu], 1u);
  }
  __syncthreads();
  unsigned cnt2[CH2];
  unsigned long long tot = 0;
  for (int j = 0; j < CH2; j++) { cnt2[j] = h2[t * CH2 + j]; tot += cnt2[j]; }
  sarr[t] = tot;
  __syncthreads();
  for (int off = 1; off < T; off <<= 1) {
    unsigned long long v = (t + off < T) ? sarr[t + off] : 0ull;
    __syncthreads();
    sarr[t] += v;
    __syncthreads();
  }
  if (k_rem > 0) {
    unsigned long long above = sarr[t] - tot;
    if (above < (unsigned long long)k_rem &&
        sarr[t] >= (unsigned long long)k_rem) {
      unsigned long long cum = above;
      for (int j = CH2 - 1; j >= 0; j--) {
        if (cum + (unsigned long long)cnt2[j] >= (unsigned long long)k_rem) {
          sB2 = t * CH2 + j;
          sk2 = (unsigned)((unsigned long long)k_rem - cum);
          break;
        }
        cum += cnt2[j];
      }
    }
  }
  __syncthreads();
  int B2 = sB2; unsigned k2r = sk2;
  double ssum = 0.0;
  if (k_rem > 0) {
    for (unsigned i = t; i < M; i += T) {
      unsigned bits = cand[i];
      int b2 = (int)((bits >> 7) & 0xFFFu);
      if (b2 > B2) ssum += (double)__uint_as_float(bits);
      else if (b2 == B2) atomicAdd(&h3[bits & 0x7Fu], 1u);
    }
  }
  for (int off = 32; off > 0; off >>= 1) ssum += __shfl_down(ssum, off);
  int wv = t >> 6, ln = t & 63;
  if (ln == 0) sws[wv] = ssum;
  __syncthreads();
  if (t == 0) {
    double sum2 = 0.0;
    for (int w = 0; w < T / 64; w++) sum2 += sws[w];
    double partial = 0.0;
    unsigned rem = k2r;
    unsigned base = (ctrl->B << 19) | ((unsigned)B2 << 7);
    for (int b = 127; b >= 0 && rem > 0; b--) {
      unsigned c = h3[b];
      if (!c) continue;
      unsigned take = (c < rem) ? c : rem;
      partial += (double)take * (double)__uint_as_float(base | (unsigned)b);
      rem -= take;
    }
    double neg_sum = ctrl->sum_above + sum2 + partial;
    double denom = (double)ctrl->pos_cnt + (double)ctrl->k + 1e-6;
    out[0] = (float)((ctrl->pos_sum + neg_sum) / denom);
  }
}

// ---------------------------------------------------------------------------
extern "C" void kernel_launch(void* const* d_in, const int* in_sizes, int n_in,
                              void* d_out, int out_size, void* d_ws, size_t ws_size,
                              hipStream_t stream) {
  const float* pred = (const float*)d_in[0];
  const float* gt   = (const float*)d_in[1];
  const float* mask = (const float*)d_in[2];
  float* out = (float*)d_out;
  int n = in_sizes[0];
  int n4 = n / 4;
  char* ws = (char*)d_ws;

  // layout: ctrl@0, hist1@256 (16KB) -> zero 16640 B
  const size_t HIST1_OFF = 256;
  const size_t ZERO_BYTES = HIST1_OFF + NBINS1 * sizeof(unsigned);   // 16640

  if (ws_size >= 32768) {
    Ctrl* ctrl = (Ctrl*)ws;
    unsigned* hist1 = (unsigned*)(ws + HIST1_OFF);
    hipMemsetAsync(d_ws, 0, ZERO_BYTES, stream);
    y1_fused<<<Y_BLOCKS, Y_THREADS, 0, stream>>>(pred, gt, mask, hist1, ctrl,
                                                 out, n4, n);
  } else {
    // fallback: exact R2 pipeline
    Ctrl* ctrl = (Ctrl*)ws;
    unsigned* hist1 = (unsigned*)(ws + 256);
    size_t coff = 256 + (size_t)NBINS1 * sizeof(unsigned);
    unsigned* cand = (unsigned*)(ws + coff);
    unsigned cap = 0;
    if (ws_size > coff + 4) {
      size_t c = (ws_size - coff) / 4;
      cap = (c > (size_t)n) ? (unsigned)n : (unsigned)c;
    }
    hipMemsetAsync(d_ws, 0, coff, stream);
    k1_hist<<<K1_BLOCKS, 256, 0, stream>>>(pred, gt, mask, hist1, ctrl, n4, n);
    k2_select_fb<<<1, 256, 0, stream>>>(hist1, ctrl);
    int blocks3 = (n4 + K3_VEC_PER_BLOCK - 1) / K3_VEC_PER_BLOCK;
    if (blocks3 < 1) blocks3 = 1;
    k3_compact<<<blocks3, 256, 0, stream>>>(pred, gt, mask, ctrl, cand, cap, n4, n);
    k4_final<<<1, 1024, 0, stream>>>(cand, ctrl, out, cap);
  }
}